// Round 5
// baseline (164.850 us; speedup 1.0000x reference)
//
#include <hip/hip_runtime.h>
#include <hip/hip_bf16.h>
#include <math.h>

typedef __bf16 bf16_t;
typedef __attribute__((ext_vector_type(8))) __bf16 bf16x8;
typedef __attribute__((ext_vector_type(4))) float f32x4;
typedef __attribute__((ext_vector_type(2))) float f32x2;

#define NB 8  // nodes per block (even; divides 25000/.. 3125 blocks)

// ---------------------------------------------------------------------------
// pack: Wp/W2p in MFMA B-fragment layout + w2an = W2 @ a_n (f32).
// ---------------------------------------------------------------------------
__global__ __launch_bounds__(256) void pack_weights_kernel(
    const float* __restrict__ W, const float* __restrict__ W2,
    const float* __restrict__ a,
    bf16_t* __restrict__ Wp, bf16_t* __restrict__ W2p,
    float* __restrict__ w2an) {
  int idx = blockIdx.x * 256 + threadIdx.x;   // grid = 64 blocks
  int j  = idx & 7;
  int l  = (idx >> 3) & 63;
  int nt = (idx >> 9) & 7;
  int kt = idx >> 12;
  int k   = kt * 32 + (l >> 4) * 8 + j;
  int col = nt * 16 + (l & 15);
  Wp[idx]  = (bf16_t)W[k * 128 + col];
  W2p[idx] = (bf16_t)W2[k * 128 + col];
  if (blockIdx.x == 0 && threadIdx.x < 128) {
    const float* r = W2 + threadIdx.x * 128;
    float s = 0.f;
    for (int c = 0; c < 128; ++c) s += r[c] * a[128 + c];
    w2an[threadIdx.x] = s;
  }
}

// ---------------------------------------------------------------------------
// gemm: out cols [col_off..col_off+128) = elu(src(N x 128) @ Wpk).
// sxv != null: also writes sx[n] = dot(x_n, a_x).
// ---------------------------------------------------------------------------
__global__ __launch_bounds__(256) void gemm_kernel(
    const float* __restrict__ src, const bf16_t* __restrict__ Wpk,
    const float* __restrict__ a,
    float* __restrict__ out, float* __restrict__ sxv, int col_off, int N) {
  __shared__ __align__(16) bf16_t As[32 * 128];
  __shared__ float sp2[2][32];
  const int t  = threadIdx.x;
  const int rb = blockIdx.x * 32;
  const int w = t >> 6, l = t & 63;

  for (int c = t; c < 512; c += 256) {
    int row = c >> 4;
    int kc  = (c & 15) * 8;
    int grow = rb + row;
    float v[8];
    if (grow < N) {
      const f32x4* p = (const f32x4*)(src + (size_t)grow * 128 + kc);
      f32x4 v0 = p[0], v1 = p[1];
      v[0]=v0[0]; v[1]=v0[1]; v[2]=v0[2]; v[3]=v0[3];
      v[4]=v1[0]; v[5]=v1[1]; v[6]=v1[2]; v[7]=v1[3];
    } else {
      for (int j = 0; j < 8; ++j) v[j] = 0.f;
    }
    bf16x8 b;
    for (int j = 0; j < 8; ++j) b[j] = (bf16_t)v[j];
    *(bf16x8*)(&As[row * 128 + (kc ^ ((row & 7) << 3))]) = b;
  }
  __syncthreads();

  const int mt = w & 1;
  const int ntg = (w >> 1) * 4;
  const int arow = mt * 16 + (l & 15);

  f32x4 acc[4] = {};
#pragma unroll
  for (int kt = 0; kt < 4; ++kt) {
    bf16x8 af = *(const bf16x8*)(&As[arow * 128 + ((kt * 32 + (l >> 4) * 8) ^ ((arow & 7) << 3))]);
#pragma unroll
    for (int i = 0; i < 4; ++i) {
      bf16x8 bfv = *(const bf16x8*)(&Wpk[((kt * 8 + (ntg + i)) * 64 + l) * 8]);
      acc[i] = __builtin_amdgcn_mfma_f32_16x16x32_bf16(af, bfv, acc[i], 0, 0, 0);
    }
  }

  if (sxv) {
    float ax[4];
#pragma unroll
    for (int i = 0; i < 4; ++i) ax[i] = a[(ntg + i) * 16 + (l & 15)];
#pragma unroll
    for (int j = 0; j < 4; ++j) {
      float p = acc[0][j]*ax[0] + acc[1][j]*ax[1] + acc[2][j]*ax[2] + acc[3][j]*ax[3];
      p += __shfl_xor(p, 1); p += __shfl_xor(p, 2);
      p += __shfl_xor(p, 4); p += __shfl_xor(p, 8);
      if ((l & 15) == 0) sp2[w >> 1][mt * 16 + (l >> 4) * 4 + j] = p;
    }
    __syncthreads();
    if (t < 32) {
      int gr = rb + t;
      if (gr < N) sxv[gr] = sp2[0][t] + sp2[1][t];
    }
  }

#pragma unroll
  for (int i = 0; i < 4; ++i) {
    int col = (ntg + i) * 16 + (l & 15);
#pragma unroll
    for (int j = 0; j < 4; ++j) {
      int row = mt * 16 + (l >> 4) * 4 + j;
      int gr = rb + row;
      if (gr < N) {
        float v = acc[i][j];
        v = v > 0.f ? v : __expf(v) - 1.f;
        __builtin_nontemporal_store(v, &out[(size_t)gr * 320 + col_off + col]);
      }
    }
  }
}

// ---------------------------------------------------------------------------
// Streaming node kernel, depth-2 prefetch (two named register sets A/B).
// Thread t owns row r=t>>3: nf cols [sub*16, +16), edge cols [sub*8, +8).
// Scores (nf·w2an + e·a_e) fused into one row-reduction. Agg via bf16 LDS.
// ---------------------------------------------------------------------------
__global__ __launch_bounds__(256) void node_kernel(
    const float* __restrict__ neigh_feat, const float* __restrict__ edge_emb,
    const float* __restrict__ a, const float* __restrict__ w2an,
    const float* __restrict__ sxv, float* __restrict__ aggbuf,
    float* __restrict__ out) {
  const int t = threadIdx.x;
  const int w = t >> 6, l = t & 63;
  const int n0 = blockIdx.x * NB;
  const int r = t >> 3, sub = t & 7;
  const int c0 = sub * 16;

  __shared__ __align__(16) bf16_t As[2][32 * 128];  // 16 KB dbuf nf (swizzled)
  __shared__ __align__(16) bf16_t Eb[2][32 * 64];   // 8 KB  dbuf edge (swizzled)
  __shared__ float srow[2][32];                     // total per-row score partial

  // loop-invariant vectors (L1/L2 hits, once per block)
  const f32x4 wn0 = *(const f32x4*)(w2an + c0);
  const f32x4 wn1 = *(const f32x4*)(w2an + c0 + 4);
  const f32x4 wn2 = *(const f32x4*)(w2an + c0 + 8);
  const f32x4 wn3 = *(const f32x4*)(w2an + c0 + 12);
  const f32x4 ae0 = *(const f32x4*)(a + 256 + sub * 8);
  const f32x4 ae1 = *(const f32x4*)(a + 256 + sub * 8 + 4);

  // swizzled LDS write offsets (bf16 elements)
  const int wrA = r * 128 + (((sub * 2) ^ (r & 7)) * 8);
  const int wrB = r * 128 + ((((sub * 2) + 1) ^ (r & 7)) * 8);
  const int wrE = r * 64 + ((sub ^ (r & 7)) * 8);

  f32x4 nA0, nA1, nA2, nA3, eA0, eA1;
  f32x4 nB0, nB1, nB2, nB3, eB0, eB1;

#define ISSUE(P, node_) do {                                               \
    const float* nf_ = neigh_feat + (size_t)(node_) * 4096 + r * 128 + c0; \
    n##P##0 = *(const f32x4*)(nf_);                                        \
    n##P##1 = *(const f32x4*)(nf_ + 4);                                    \
    n##P##2 = *(const f32x4*)(nf_ + 8);                                    \
    n##P##3 = *(const f32x4*)(nf_ + 12);                                   \
    const float* ee_ = edge_emb + (size_t)(node_) * 2048 + r * 64 + sub * 8; \
    e##P##0 = *(const f32x4*)(ee_);                                        \
    e##P##1 = *(const f32x4*)(ee_ + 4);                                    \
  } while (0)

#define BODY(P, b, kk) do {                                                 \
    const int node = n0 + (kk);                                             \
    {                                                                       \
      float p = n##P##0[0]*wn0[0] + n##P##0[1]*wn0[1] + n##P##0[2]*wn0[2] + n##P##0[3]*wn0[3] \
              + n##P##1[0]*wn1[0] + n##P##1[1]*wn1[1] + n##P##1[2]*wn1[2] + n##P##1[3]*wn1[3] \
              + n##P##2[0]*wn2[0] + n##P##2[1]*wn2[1] + n##P##2[2]*wn2[2] + n##P##2[3]*wn2[3] \
              + n##P##3[0]*wn3[0] + n##P##3[1]*wn3[1] + n##P##3[2]*wn3[2] + n##P##3[3]*wn3[3] \
              + e##P##0[0]*ae0[0] + e##P##0[1]*ae0[1] + e##P##0[2]*ae0[2] + e##P##0[3]*ae0[3] \
              + e##P##1[0]*ae1[0] + e##P##1[1]*ae1[1] + e##P##1[2]*ae1[2] + e##P##1[3]*ae1[3]; \
      p += __shfl_xor(p, 1); p += __shfl_xor(p, 2); p += __shfl_xor(p, 4);  \
      if (sub == 0) srow[b][r] = p;                                         \
      bf16x8 x0, x1, xe;                                                    \
      _Pragma("unroll")                                                     \
      for (int j = 0; j < 4; ++j) {                                         \
        x0[j] = (bf16_t)n##P##0[j]; x0[j+4] = (bf16_t)n##P##1[j];           \
        x1[j] = (bf16_t)n##P##2[j]; x1[j+4] = (bf16_t)n##P##3[j];           \
        xe[j] = (bf16_t)e##P##0[j]; xe[j+4] = (bf16_t)e##P##1[j];           \
      }                                                                     \
      *(bf16x8*)(&As[b][wrA]) = x0;                                         \
      *(bf16x8*)(&As[b][wrB]) = x1;                                         \
      *(bf16x8*)(&Eb[b][wrE]) = xe;                                         \
    }                                                                       \
    if ((kk) + 2 < NB) ISSUE(P, node + 2);                                  \
    __syncthreads();                                                        \
    float av;                                                               \
    {                                                                       \
      const float sx = sxv[node];                                           \
      float e = srow[b][l & 31] + sx;                                       \
      e = e > 0.f ? e : 0.8f * e;                                           \
      float m = e;                                                          \
      m = fmaxf(m, __shfl_xor(m, 1));                                       \
      m = fmaxf(m, __shfl_xor(m, 2));                                       \
      m = fmaxf(m, __shfl_xor(m, 4));                                       \
      m = fmaxf(m, __shfl_xor(m, 8));                                       \
      m = fmaxf(m, __shfl_xor(m, 16));                                      \
      float pe = __expf(e - m);                                             \
      float s2 = pe;                                                        \
      s2 += __shfl_xor(s2, 1);                                              \
      s2 += __shfl_xor(s2, 2);                                              \
      s2 += __shfl_xor(s2, 4);                                              \
      s2 += __shfl_xor(s2, 8);                                              \
      s2 += __shfl_xor(s2, 16);                                             \
      av = pe / s2;                                                         \
    }                                                                       \
    if (w == 0) {                                                           \
      const int gg = l >> 2, boff = (l & 3) * 4;                            \
      const char* base = (const char*)As[b];                                \
      float a0 = 0.f, a1 = 0.f;                                             \
      _Pragma("unroll")                                                     \
      for (int s = 0; s < 32; ++s) {                                        \
        unsigned u = *(const unsigned*)(base + s * 256 + ((gg ^ (s & 7)) * 16) + boff); \
        float as = __shfl(av, s);                                           \
        a0 = fmaf(as, __uint_as_float(u << 16), a0);                        \
        a1 = fmaf(as, __uint_as_float(u & 0xffff0000u), a1);                \
      }                                                                     \
      f32x2 st = {a0, a1};                                                  \
      *(f32x2*)(aggbuf + (size_t)node * 128 + 2 * l) = st;                  \
    } else if (w == 1 && l < 32) {                                          \
      const int gg = l >> 2, boff = (l & 3) * 4;                            \
      const char* base = (const char*)Eb[b];                                \
      float a0 = 0.f, a1 = 0.f;                                             \
      _Pragma("unroll")                                                     \
      for (int s = 0; s < 32; ++s) {                                        \
        unsigned u = *(const unsigned*)(base + s * 128 + ((gg ^ (s & 7)) * 16) + boff); \
        float as = __shfl(av, s);                                           \
        a0 = fmaf(as, __uint_as_float(u << 16), a0);                        \
        a1 = fmaf(as, __uint_as_float(u & 0xffff0000u), a1);                \
      }                                                                     \
      a0 = a0 > 0.f ? a0 : __expf(a0) - 1.f;                                \
      a1 = a1 > 0.f ? a1 : __expf(a1) - 1.f;                                \
      f32x2 st = {a0, a1};                                                  \
      __builtin_nontemporal_store(st, (f32x2*)(out + (size_t)node * 320 + 256 + 2 * l)); \
    }                                                                       \
  } while (0)

  // prologue: two node-loads in flight
  ISSUE(A, n0);
  ISSUE(B, n0 + 1);

#pragma unroll 1
  for (int k = 0; k < NB; k += 2) {
    BODY(A, 0, k);
    BODY(B, 1, k + 1);
  }
#undef BODY
#undef ISSUE
}

// ---------------------------------------------------------------------------
extern "C" void kernel_launch(void* const* d_in, const int* in_sizes, int n_in,
                              void* d_out, int out_size, void* d_ws, size_t ws_size,
                              hipStream_t stream) {
  const float* input = (const float*)d_in[0];
  const float* neigh = (const float*)d_in[1];
  const float* edge  = (const float*)d_in[2];
  // d_in[3] = mask (unused by the reference computation)
  const float* W     = (const float*)d_in[4];
  const float* W2    = (const float*)d_in[5];
  const float* a     = (const float*)d_in[6];
  float* out = (float*)d_out;

  const int N = in_sizes[0] / 128;  // 25000

  bf16_t* W2p  = (bf16_t*)d_ws;                          // 32 KB
  bf16_t* Wp   = W2p + 16384;                            // 32 KB
  float*  w2an = (float*)((char*)d_ws + 65536);          // 512 B
  float*  sxv  = (float*)((char*)d_ws + 66560);          // N f32
  float*  agg  = (float*)((char*)d_ws + 262144);         // N*128 f32 (12.8 MB)

  pack_weights_kernel<<<64, 256, 0, stream>>>(W, W2, a, Wp, W2p, w2an);
  gemm_kernel<<<(N + 31) / 32, 256, 0, stream>>>(input, Wp, a, out, sxv, 0, N);
  node_kernel<<<N / NB, 256, 0, stream>>>(neigh, edge, a, w2an, sxv, agg, out);
  gemm_kernel<<<(N + 31) / 32, 256, 0, stream>>>(agg, W2p, a, out, nullptr, 128, N);
}

// Round 6
// 163.849 us; speedup vs baseline: 1.0061x; 1.0061x over previous
//
#include <hip/hip_runtime.h>
#include <hip/hip_bf16.h>
#include <math.h>

typedef __bf16 bf16_t;
typedef __attribute__((ext_vector_type(8))) __bf16 bf16x8;
typedef __attribute__((ext_vector_type(4))) float f32x4;

#define NB 8  // nodes per block; 25000/8 = 3125 blocks

// ---------------------------------------------------------------------------
// pack: Wp/W2p in MFMA B-fragment layout + w2an = W2 @ a_n (f32).
// ---------------------------------------------------------------------------
__global__ __launch_bounds__(256) void pack_weights_kernel(
    const float* __restrict__ W, const float* __restrict__ W2,
    const float* __restrict__ a,
    bf16_t* __restrict__ Wp, bf16_t* __restrict__ W2p,
    float* __restrict__ w2an) {
  int idx = blockIdx.x * 256 + threadIdx.x;   // grid = 64 blocks
  int j  = idx & 7;
  int l  = (idx >> 3) & 63;
  int nt = (idx >> 9) & 7;
  int kt = idx >> 12;
  int k   = kt * 32 + (l >> 4) * 8 + j;
  int col = nt * 16 + (l & 15);
  Wp[idx]  = (bf16_t)W[k * 128 + col];
  W2p[idx] = (bf16_t)W2[k * 128 + col];
  if (blockIdx.x == 0 && threadIdx.x < 128) {
    const float* r = W2 + threadIdx.x * 128;
    float s = 0.f;
    for (int c = 0; c < 128; ++c) s += r[c] * a[128 + c];
    w2an[threadIdx.x] = s;
  }
}

// ---------------------------------------------------------------------------
// gemm: out cols [col_off..col_off+128) = elu(src(N x 128) @ Wpk).
// sxv != null: also writes sx[n] = dot(x_n, a_x).
// ---------------------------------------------------------------------------
__global__ __launch_bounds__(256) void gemm_kernel(
    const float* __restrict__ src, const bf16_t* __restrict__ Wpk,
    const float* __restrict__ a,
    float* __restrict__ out, float* __restrict__ sxv, int col_off, int N) {
  __shared__ __align__(16) bf16_t As[32 * 128];
  __shared__ float sp2[2][32];
  const int t  = threadIdx.x;
  const int rb = blockIdx.x * 32;
  const int w = t >> 6, l = t & 63;

  for (int c = t; c < 512; c += 256) {
    int row = c >> 4;
    int kc  = (c & 15) * 8;
    int grow = rb + row;
    float v[8];
    if (grow < N) {
      const f32x4* p = (const f32x4*)(src + (size_t)grow * 128 + kc);
      f32x4 v0 = p[0], v1 = p[1];
      v[0]=v0[0]; v[1]=v0[1]; v[2]=v0[2]; v[3]=v0[3];
      v[4]=v1[0]; v[5]=v1[1]; v[6]=v1[2]; v[7]=v1[3];
    } else {
      for (int j = 0; j < 8; ++j) v[j] = 0.f;
    }
    bf16x8 b;
    for (int j = 0; j < 8; ++j) b[j] = (bf16_t)v[j];
    *(bf16x8*)(&As[row * 128 + (kc ^ ((row & 7) << 3))]) = b;
  }
  __syncthreads();

  const int mt = w & 1;
  const int ntg = (w >> 1) * 4;
  const int arow = mt * 16 + (l & 15);

  f32x4 acc[4] = {};
#pragma unroll
  for (int kt = 0; kt < 4; ++kt) {
    bf16x8 af = *(const bf16x8*)(&As[arow * 128 + ((kt * 32 + (l >> 4) * 8) ^ ((arow & 7) << 3))]);
#pragma unroll
    for (int i = 0; i < 4; ++i) {
      bf16x8 bfv = *(const bf16x8*)(&Wpk[((kt * 8 + (ntg + i)) * 64 + l) * 8]);
      acc[i] = __builtin_amdgcn_mfma_f32_16x16x32_bf16(af, bfv, acc[i], 0, 0, 0);
    }
  }

  if (sxv) {
    float ax[4];
#pragma unroll
    for (int i = 0; i < 4; ++i) ax[i] = a[(ntg + i) * 16 + (l & 15)];
#pragma unroll
    for (int j = 0; j < 4; ++j) {
      float p = acc[0][j]*ax[0] + acc[1][j]*ax[1] + acc[2][j]*ax[2] + acc[3][j]*ax[3];
      p += __shfl_xor(p, 1); p += __shfl_xor(p, 2);
      p += __shfl_xor(p, 4); p += __shfl_xor(p, 8);
      if ((l & 15) == 0) sp2[w >> 1][mt * 16 + (l >> 4) * 4 + j] = p;
    }
    __syncthreads();
    if (t < 32) {
      int gr = rb + t;
      if (gr < N) sxv[gr] = sp2[0][t] + sp2[1][t];
    }
  }

#pragma unroll
  for (int i = 0; i < 4; ++i) {
    int col = (ntg + i) * 16 + (l & 15);
#pragma unroll
    for (int j = 0; j < 4; ++j) {
      int row = mt * 16 + (l >> 4) * 4 + j;
      int gr = rb + row;
      if (gr < N) {
        float v = acc[i][j];
        v = v > 0.f ? v : __expf(v) - 1.f;
        __builtin_nontemporal_store(v, &out[(size_t)gr * 320 + col_off + col]);
      }
    }
  }
}

// ---------------------------------------------------------------------------
// Streaming node kernel: DENSE per-instruction loads (each wave-instruction
// covers one contiguous 1 KB block). All data stays in registers; scores and
// aggregation via in-wave shfl reductions + 3 KB LDS cross-wave combine.
//   nf  instr j (0..3): float4 at node*4096 + 1024j + 4t
//       -> row = 8j + 2w + (l>>5), cols 4(l&31)..+3
//   ee  instr j (0..1): float4 at node*2048 + 1024j + 4t
//       -> row = 16j + 4w + (l>>4), cols 4(l&15)..+3
// ---------------------------------------------------------------------------
__global__ __launch_bounds__(256) void node_kernel(
    const float* __restrict__ neigh_feat, const float* __restrict__ edge_emb,
    const float* __restrict__ a, const float* __restrict__ w2an,
    const float* __restrict__ sxv, float* __restrict__ aggbuf,
    float* __restrict__ out) {
  const int t = threadIdx.x;
  const int w = t >> 6, l = t & 63;
  const int n0 = blockIdx.x * NB;

  __shared__ float srow[32];                  // per-row nf-score
  __shared__ float se[32];                    // per-row edge-score
  __shared__ __align__(16) f32x4 nag[4][32];  // 2 KB nf-agg wave partials
  __shared__ __align__(16) f32x4 eag[4][16];  // 1 KB edge-agg wave partials

  const int q = l & 31;   // nf col-group (cols 4q..4q+3)
  const int h = l >> 5;   // nf row half
  const int p = l & 15;   // edge col-group
  const int g = l >> 4;   // edge row sub

  const f32x4 wn = *(const f32x4*)(w2an + 4 * q);
  const f32x4 ae = *(const f32x4*)(a + 256 + 4 * p);

  f32x4 nA[4], eA[2], nB[4], eB[2];
  float sxA, sxB;

#define ISSUE(P, node_) do {                                              \
    const float* nf_ = neigh_feat + (size_t)(node_) * 4096 + 4 * t;       \
    n##P[0] = *(const f32x4*)(nf_);                                       \
    n##P[1] = *(const f32x4*)(nf_ + 1024);                                \
    n##P[2] = *(const f32x4*)(nf_ + 2048);                                \
    n##P[3] = *(const f32x4*)(nf_ + 3072);                                \
    const float* ee_ = edge_emb + (size_t)(node_) * 2048 + 4 * t;         \
    e##P[0] = *(const f32x4*)(ee_);                                       \
    e##P[1] = *(const f32x4*)(ee_ + 1024);                                \
    sx##P = sxv[node_];                                                   \
  } while (0)

#define BODY(P, kk) do {                                                  \
    const int node = n0 + (kk);                                           \
    /* ---- scores: in-wave row reductions ---- */                        \
    _Pragma("unroll")                                                     \
    for (int j = 0; j < 4; ++j) {                                         \
      float s = n##P[j][0]*wn[0] + n##P[j][1]*wn[1]                       \
              + n##P[j][2]*wn[2] + n##P[j][3]*wn[3];                      \
      s += __shfl_xor(s, 1);  s += __shfl_xor(s, 2);                      \
      s += __shfl_xor(s, 4);  s += __shfl_xor(s, 8);                      \
      s += __shfl_xor(s, 16);                                             \
      if (q == 0) srow[8*j + 2*w + h] = s;                                \
    }                                                                     \
    _Pragma("unroll")                                                     \
    for (int j = 0; j < 2; ++j) {                                         \
      float s = e##P[j][0]*ae[0] + e##P[j][1]*ae[1]                       \
              + e##P[j][2]*ae[2] + e##P[j][3]*ae[3];                      \
      s += __shfl_xor(s, 1);  s += __shfl_xor(s, 2);                      \
      s += __shfl_xor(s, 4);  s += __shfl_xor(s, 8);                      \
      if (p == 0) se[16*j + 4*w + g] = s;                                 \
    }                                                                     \
    __syncthreads();                                                      \
    /* ---- leaky + softmax(32), redundant per wave; av = att[q] ---- */  \
    float av;                                                             \
    {                                                                     \
      float e0 = srow[q] + se[q] + sx##P;                                 \
      e0 = e0 > 0.f ? e0 : 0.8f * e0;                                     \
      float m = e0;                                                       \
      m = fmaxf(m, __shfl_xor(m, 1));                                     \
      m = fmaxf(m, __shfl_xor(m, 2));                                     \
      m = fmaxf(m, __shfl_xor(m, 4));                                     \
      m = fmaxf(m, __shfl_xor(m, 8));                                     \
      m = fmaxf(m, __shfl_xor(m, 16));                                    \
      float pe = __expf(e0 - m);                                          \
      float s2 = pe;                                                      \
      s2 += __shfl_xor(s2, 1);                                            \
      s2 += __shfl_xor(s2, 2);                                            \
      s2 += __shfl_xor(s2, 4);                                            \
      s2 += __shfl_xor(s2, 8);                                            \
      s2 += __shfl_xor(s2, 16);                                           \
      av = pe / s2;                                                       \
    }                                                                     \
    /* ---- aggregation from registers ---- */                            \
    {                                                                     \
      f32x4 pn = {0.f, 0.f, 0.f, 0.f};                                    \
      _Pragma("unroll")                                                   \
      for (int j = 0; j < 4; ++j) {                                       \
        float as = __shfl(av, 8*j + 2*w + h);                             \
        pn += as * n##P[j];                                               \
      }                                                                   \
      pn[0] += __shfl_xor(pn[0], 32);                                     \
      pn[1] += __shfl_xor(pn[1], 32);                                     \
      pn[2] += __shfl_xor(pn[2], 32);                                     \
      pn[3] += __shfl_xor(pn[3], 32);                                     \
      if (h == 0) nag[w][q] = pn;                                         \
      f32x4 pv = {0.f, 0.f, 0.f, 0.f};                                    \
      _Pragma("unroll")                                                   \
      for (int j = 0; j < 2; ++j) {                                       \
        float as = __shfl(av, 16*j + 4*w + g);                            \
        pv += as * e##P[j];                                               \
      }                                                                   \
      pv[0] += __shfl_xor(pv[0], 16);                                     \
      pv[1] += __shfl_xor(pv[1], 16);                                     \
      pv[2] += __shfl_xor(pv[2], 16);                                     \
      pv[3] += __shfl_xor(pv[3], 16);                                     \
      pv[0] += __shfl_xor(pv[0], 32);                                     \
      pv[1] += __shfl_xor(pv[1], 32);                                     \
      pv[2] += __shfl_xor(pv[2], 32);                                     \
      pv[3] += __shfl_xor(pv[3], 32);                                     \
      if (l < 16) eag[w][p] = pv;                                         \
    }                                                                     \
    /* ---- reissue this set for node+2 (flies under next BODY) ---- */   \
    if ((kk) + 2 < NB) ISSUE(P, node + 2);                                \
    __syncthreads();                                                      \
    /* ---- final combine + stores ---- */                                \
    if (t < 128) {                                                        \
      const float* f = (const float*)nag;                                 \
      float v = f[t] + f[128 + t] + f[256 + t] + f[384 + t];              \
      aggbuf[(size_t)node * 128 + t] = v;                                 \
    } else if (t < 192) {                                                 \
      int c = t - 128;                                                    \
      const float* f = (const float*)eag;                                 \
      float v = f[c] + f[64 + c] + f[128 + c] + f[192 + c];               \
      v = v > 0.f ? v : __expf(v) - 1.f;                                  \
      __builtin_nontemporal_store(v, out + (size_t)node * 320 + 256 + c); \
    }                                                                     \
  } while (0)

  ISSUE(A, n0);
  ISSUE(B, n0 + 1);

#pragma unroll 1
  for (int k = 0; k < NB; k += 2) {
    BODY(A, k);
    BODY(B, k + 1);
  }
#undef BODY
#undef ISSUE
}

// ---------------------------------------------------------------------------
extern "C" void kernel_launch(void* const* d_in, const int* in_sizes, int n_in,
                              void* d_out, int out_size, void* d_ws, size_t ws_size,
                              hipStream_t stream) {
  const float* input = (const float*)d_in[0];
  const float* neigh = (const float*)d_in[1];
  const float* edge  = (const float*)d_in[2];
  // d_in[3] = mask (unused by the reference computation)
  const float* W     = (const float*)d_in[4];
  const float* W2    = (const float*)d_in[5];
  const float* a     = (const float*)d_in[6];
  float* out = (float*)d_out;

  const int N = in_sizes[0] / 128;  // 25000

  bf16_t* W2p  = (bf16_t*)d_ws;                          // 32 KB
  bf16_t* Wp   = W2p + 16384;                            // 32 KB
  float*  w2an = (float*)((char*)d_ws + 65536);          // 512 B
  float*  sxv  = (float*)((char*)d_ws + 66560);          // N f32
  float*  agg  = (float*)((char*)d_ws + 262144);         // N*128 f32 (12.8 MB)

  pack_weights_kernel<<<64, 256, 0, stream>>>(W, W2, a, Wp, W2p, w2an);
  gemm_kernel<<<(N + 31) / 32, 256, 0, stream>>>(input, Wp, a, out, sxv, 0, N);
  node_kernel<<<N / NB, 256, 0, stream>>>(neigh, edge, a, w2an, sxv, agg, out);
  gemm_kernel<<<(N + 31) / 32, 256, 0, stream>>>(agg, W2p, a, out, nullptr, 128, N);
}

// Round 8
// 149.671 us; speedup vs baseline: 1.1014x; 1.0947x over previous
//
#include <hip/hip_runtime.h>
#include <hip/hip_bf16.h>
#include <math.h>

typedef __bf16 bf16_t;
typedef __attribute__((ext_vector_type(8))) __bf16 bf16x8;
typedef __attribute__((ext_vector_type(4))) __bf16 bf16x4;
typedef __attribute__((ext_vector_type(4))) float f32x4;

#define NB 8  // nodes per block; 25000/8 = 3125 blocks

// ---------------------------------------------------------------------------
// pack: Wp/W2p in MFMA B-fragment layout + w2an = W2@a_n + wax = W@a_x.
//   Wp[((kt*8+nt)*64+l)*8+j] = W[(kt*32+(l>>4)*8+j)*128 + nt*16+(l&15)]
// ---------------------------------------------------------------------------
__global__ __launch_bounds__(256) void pack_weights_kernel(
    const float* __restrict__ W, const float* __restrict__ W2,
    const float* __restrict__ a,
    bf16_t* __restrict__ Wp, bf16_t* __restrict__ W2p,
    float* __restrict__ w2an, float* __restrict__ wax) {
  int idx = blockIdx.x * 256 + threadIdx.x;   // grid = 64 blocks
  int j  = idx & 7;
  int l  = (idx >> 3) & 63;
  int nt = (idx >> 9) & 7;
  int kt = idx >> 12;
  int k   = kt * 32 + (l >> 4) * 8 + j;
  int col = nt * 16 + (l & 15);
  Wp[idx]  = (bf16_t)W[k * 128 + col];
  W2p[idx] = (bf16_t)W2[k * 128 + col];
  if (blockIdx.x == 0 && threadIdx.x < 128) {
    const float* r = W2 + threadIdx.x * 128;
    float s = 0.f;
    for (int c = 0; c < 128; ++c) s += r[c] * a[128 + c];
    w2an[threadIdx.x] = s;                    // w2an[k] = dot(W2[k,:], a_n)
  }
  if (blockIdx.x == 1 && threadIdx.x < 128) {
    const float* r = W + threadIdx.x * 128;
    float s = 0.f;
    for (int c = 0; c < 128; ++c) s += r[c] * a[c];
    wax[threadIdx.x] = s;                     // wax[k] = dot(W[k,:], a_x)
  }
}

// ---------------------------------------------------------------------------
// Über node kernel: per block of 8 nodes does EVERYTHING.
//   phase 0: stage 8 input rows -> Ax tile; sx[r] = input_r . wax (in-wave)
//   phase 1: x = input@W via M=16 MFMA tile -> elu -> out[0:128)
//   loop   : stream 8 nodes (scores/softmax/agg -> Agg LDS, e_agg -> out)
//   epilog : h' = Agg@W2 via M=16 MFMA tile -> elu -> out[128:256)
// ---------------------------------------------------------------------------
__global__ __launch_bounds__(256) void node_kernel(
    const float* __restrict__ input,
    const float* __restrict__ neigh_feat, const float* __restrict__ edge_emb,
    const float* __restrict__ a, const float* __restrict__ w2an,
    const float* __restrict__ wax,
    const bf16_t* __restrict__ Wp, const bf16_t* __restrict__ W2p,
    float* __restrict__ out) {
  const int t = threadIdx.x;
  const int w = t >> 6, l = t & 63;
  const int n0 = blockIdx.x * NB;

  __shared__ __align__(16) bf16_t Ax[16 * 128];  // 4 KB x-GEMM A (rows 8-15 zero)
  __shared__ __align__(16) bf16_t Ah[16 * 128];  // 4 KB h'-GEMM A (rows 8-15 zero)
  __shared__ float Agg[8][128];                  // 4 KB per-node agg rows
  __shared__ float srow[32], se[32];
  __shared__ __align__(16) f32x4 nag[4][32];     // 2 KB
  __shared__ __align__(16) f32x4 eag[4][16];     // 1 KB
  __shared__ float sxs[8];

  const int q = l & 31;   // nf col-group (cols 4q..4q+3)
  const int h = l >> 5;   // nf row half
  const int p = l & 15;   // edge col-group
  const int g = l >> 4;   // edge row sub

  const f32x4 wn = *(const f32x4*)(w2an + 4 * q);
  const f32x4 ae = *(const f32x4*)(a + 256 + 4 * p);

  f32x4 nA[4], eA[2], nB[4], eB[2];

#define ISSUE(P, node_) do {                                              \
    const float* nf_ = neigh_feat + (size_t)(node_) * 4096 + 4 * t;       \
    n##P[0] = *(const f32x4*)(nf_);                                       \
    n##P[1] = *(const f32x4*)(nf_ + 1024);                                \
    n##P[2] = *(const f32x4*)(nf_ + 2048);                                \
    n##P[3] = *(const f32x4*)(nf_ + 3072);                                \
    const float* ee_ = edge_emb + (size_t)(node_) * 2048 + 4 * t;         \
    e##P[0] = *(const f32x4*)(ee_);                                       \
    e##P[1] = *(const f32x4*)(ee_ + 1024);                                \
  } while (0)

  ISSUE(A, n0);
  ISSUE(B, n0 + 1);

  // ---- phase 0: input rows -> Ax (swizzled bf16), sx, zero upper tiles ----
  {
    const int r2 = t >> 5;             // 0..7 (== 2w+h)
    const int c0 = 4 * (t & 31);
    f32x4 iv = *(const f32x4*)(input + (size_t)(n0 + r2) * 128 + c0);
    f32x4 wv = *(const f32x4*)(wax + c0);
    float s = iv[0]*wv[0] + iv[1]*wv[1] + iv[2]*wv[2] + iv[3]*wv[3];
    s += __shfl_xor(s, 1);  s += __shfl_xor(s, 2);  s += __shfl_xor(s, 4);
    s += __shfl_xor(s, 8);  s += __shfl_xor(s, 16);
    if ((l & 31) == 0) sxs[r2] = s;
    bf16x4 b;
#pragma unroll
    for (int j = 0; j < 4; ++j) b[j] = (bf16_t)iv[j];
    const int gg = (t & 31) >> 1;      // 16B-granule index (0..15)
    *(bf16x4*)(&Ax[r2 * 128 + ((gg ^ r2) << 3) + 4 * (t & 1)]) = b;
    bf16x4 z = {(bf16_t)0.f, (bf16_t)0.f, (bf16_t)0.f, (bf16_t)0.f};
    *(bf16x4*)(&Ax[1024 + 4 * t]) = z;   // rows 8-15 zero
    *(bf16x4*)(&Ah[1024 + 4 * t]) = z;
  }
  __syncthreads();

  // ---- phase 1: x GEMM (one M=16 tile; wave w owns col-tiles 2w, 2w+1) ----
  {
    const int arow = l & 15;
    f32x4 acc0 = {}, acc1 = {};
#pragma unroll
    for (int kt = 0; kt < 4; ++kt) {
      bf16x8 af = *(const bf16x8*)(&Ax[arow * 128 + ((kt * 32 + (l >> 4) * 8) ^ ((arow & 7) << 3))]);
      bf16x8 b0 = *(const bf16x8*)(&Wp[((kt * 8 + 2 * w) * 64 + l) * 8]);
      bf16x8 b1 = *(const bf16x8*)(&Wp[((kt * 8 + 2 * w + 1) * 64 + l) * 8]);
      acc0 = __builtin_amdgcn_mfma_f32_16x16x32_bf16(af, b0, acc0, 0, 0, 0);
      acc1 = __builtin_amdgcn_mfma_f32_16x16x32_bf16(af, b1, acc1, 0, 0, 0);
    }
    if ((l >> 4) < 2) {
#pragma unroll
      for (int j = 0; j < 4; ++j) {
        int row = (l >> 4) * 4 + j;    // 0..7 = node index in block
        float v0 = acc0[j];
        v0 = v0 > 0.f ? v0 : __expf(v0) - 1.f;
        __builtin_nontemporal_store(v0, out + (size_t)(n0 + row) * 320 + 2 * w * 16 + (l & 15));
        float v1 = acc1[j];
        v1 = v1 > 0.f ? v1 : __expf(v1) - 1.f;
        __builtin_nontemporal_store(v1, out + (size_t)(n0 + row) * 320 + (2 * w + 1) * 16 + (l & 15));
      }
    }
  }

#define BODY(P, kk) do {                                                  \
    const int node = n0 + (kk);                                           \
    _Pragma("unroll")                                                     \
    for (int j = 0; j < 4; ++j) {                                         \
      float s = n##P[j][0]*wn[0] + n##P[j][1]*wn[1]                       \
              + n##P[j][2]*wn[2] + n##P[j][3]*wn[3];                      \
      s += __shfl_xor(s, 1);  s += __shfl_xor(s, 2);                      \
      s += __shfl_xor(s, 4);  s += __shfl_xor(s, 8);                      \
      s += __shfl_xor(s, 16);                                             \
      if (q == 0) srow[8*j + 2*w + h] = s;                                \
    }                                                                     \
    _Pragma("unroll")                                                     \
    for (int j = 0; j < 2; ++j) {                                         \
      float s = e##P[j][0]*ae[0] + e##P[j][1]*ae[1]                       \
              + e##P[j][2]*ae[2] + e##P[j][3]*ae[3];                      \
      s += __shfl_xor(s, 1);  s += __shfl_xor(s, 2);                      \
      s += __shfl_xor(s, 4);  s += __shfl_xor(s, 8);                      \
      if (p == 0) se[16*j + 4*w + g] = s;                                 \
    }                                                                     \
    __syncthreads();                                                      \
    float av;                                                             \
    {                                                                     \
      float e0 = srow[q] + se[q] + sxs[kk];                               \
      e0 = e0 > 0.f ? e0 : 0.8f * e0;                                     \
      float m = e0;                                                       \
      m = fmaxf(m, __shfl_xor(m, 1));                                     \
      m = fmaxf(m, __shfl_xor(m, 2));                                     \
      m = fmaxf(m, __shfl_xor(m, 4));                                     \
      m = fmaxf(m, __shfl_xor(m, 8));                                     \
      m = fmaxf(m, __shfl_xor(m, 16));                                    \
      float pe = __expf(e0 - m);                                          \
      float s2 = pe;                                                      \
      s2 += __shfl_xor(s2, 1);                                            \
      s2 += __shfl_xor(s2, 2);                                            \
      s2 += __shfl_xor(s2, 4);                                            \
      s2 += __shfl_xor(s2, 8);                                            \
      s2 += __shfl_xor(s2, 16);                                           \
      av = pe / s2;                                                       \
    }                                                                     \
    {                                                                     \
      f32x4 pn = {0.f, 0.f, 0.f, 0.f};                                    \
      _Pragma("unroll")                                                   \
      for (int j = 0; j < 4; ++j) {                                       \
        float as = __shfl(av, 8*j + 2*w + h);                             \
        pn += as * n##P[j];                                               \
      }                                                                   \
      pn[0] += __shfl_xor(pn[0], 32);                                     \
      pn[1] += __shfl_xor(pn[1], 32);                                     \
      pn[2] += __shfl_xor(pn[2], 32);                                     \
      pn[3] += __shfl_xor(pn[3], 32);                                     \
      if (h == 0) nag[w][q] = pn;                                         \
      f32x4 pv = {0.f, 0.f, 0.f, 0.f};                                    \
      _Pragma("unroll")                                                   \
      for (int j = 0; j < 2; ++j) {                                       \
        float as = __shfl(av, 16*j + 4*w + g);                            \
        pv += as * e##P[j];                                               \
      }                                                                   \
      pv[0] += __shfl_xor(pv[0], 16);                                     \
      pv[1] += __shfl_xor(pv[1], 16);                                     \
      pv[2] += __shfl_xor(pv[2], 16);                                     \
      pv[3] += __shfl_xor(pv[3], 16);                                     \
      pv[0] += __shfl_xor(pv[0], 32);                                     \
      pv[1] += __shfl_xor(pv[1], 32);                                     \
      pv[2] += __shfl_xor(pv[2], 32);                                     \
      pv[3] += __shfl_xor(pv[3], 32);                                     \
      if (l < 16) eag[w][p] = pv;                                         \
    }                                                                     \
    if ((kk) + 2 < NB) ISSUE(P, node + 2);                                \
    __syncthreads();                                                      \
    if (t < 128) {                                                        \
      const float* f = (const float*)nag;                                 \
      Agg[kk][t] = f[t] + f[128 + t] + f[256 + t] + f[384 + t];           \
    } else if (t < 192) {                                                 \
      int c = t - 128;                                                    \
      const float* f = (const float*)eag;                                 \
      float v = f[c] + f[64 + c] + f[128 + c] + f[192 + c];               \
      v = v > 0.f ? v : __expf(v) - 1.f;                                  \
      __builtin_nontemporal_store(v, out + (size_t)node * 320 + 256 + c); \
    }                                                                     \
  } while (0)

#pragma unroll 1
  for (int k = 0; k < NB; k += 2) {
    BODY(A, k);
    BODY(B, k + 1);
  }
#undef BODY
#undef ISSUE

  // FIX (R7 bug): the loop's final Agg[kk][*] combine-writes happen AFTER the
  // last in-BODY barrier; the epilogue below reads Agg from different threads.
  __syncthreads();

  // ---- epilogue: Agg -> Ah (swizzled bf16), then h' = Agg @ W2 ----
  {
    const int r2 = t >> 5;
    const int c0 = 4 * (t & 31);
    f32x4 v = *(const f32x4*)(&Agg[r2][c0]);
    bf16x4 b;
#pragma unroll
    for (int j = 0; j < 4; ++j) b[j] = (bf16_t)v[j];
    const int gg = (t & 31) >> 1;
    *(bf16x4*)(&Ah[r2 * 128 + ((gg ^ r2) << 3) + 4 * (t & 1)]) = b;
  }
  __syncthreads();
  {
    const int arow = l & 15;
    f32x4 acc0 = {}, acc1 = {};
#pragma unroll
    for (int kt = 0; kt < 4; ++kt) {
      bf16x8 af = *(const bf16x8*)(&Ah[arow * 128 + ((kt * 32 + (l >> 4) * 8) ^ ((arow & 7) << 3))]);
      bf16x8 b0 = *(const bf16x8*)(&W2p[((kt * 8 + 2 * w) * 64 + l) * 8]);
      bf16x8 b1 = *(const bf16x8*)(&W2p[((kt * 8 + 2 * w + 1) * 64 + l) * 8]);
      acc0 = __builtin_amdgcn_mfma_f32_16x16x32_bf16(af, b0, acc0, 0, 0, 0);
      acc1 = __builtin_amdgcn_mfma_f32_16x16x32_bf16(af, b1, acc1, 0, 0, 0);
    }
    if ((l >> 4) < 2) {
#pragma unroll
      for (int j = 0; j < 4; ++j) {
        int row = (l >> 4) * 4 + j;
        float v0 = acc0[j];
        v0 = v0 > 0.f ? v0 : __expf(v0) - 1.f;
        __builtin_nontemporal_store(v0, out + (size_t)(n0 + row) * 320 + 128 + 2 * w * 16 + (l & 15));
        float v1 = acc1[j];
        v1 = v1 > 0.f ? v1 : __expf(v1) - 1.f;
        __builtin_nontemporal_store(v1, out + (size_t)(n0 + row) * 320 + 128 + (2 * w + 1) * 16 + (l & 15));
      }
    }
  }
}

// ---------------------------------------------------------------------------
extern "C" void kernel_launch(void* const* d_in, const int* in_sizes, int n_in,
                              void* d_out, int out_size, void* d_ws, size_t ws_size,
                              hipStream_t stream) {
  const float* input = (const float*)d_in[0];
  const float* neigh = (const float*)d_in[1];
  const float* edge  = (const float*)d_in[2];
  // d_in[3] = mask (unused by the reference computation)
  const float* W     = (const float*)d_in[4];
  const float* W2    = (const float*)d_in[5];
  const float* a     = (const float*)d_in[6];
  float* out = (float*)d_out;

  const int N = in_sizes[0] / 128;  // 25000

  bf16_t* W2p  = (bf16_t*)d_ws;                          // 32 KB
  bf16_t* Wp   = W2p + 16384;                            // 32 KB
  float*  w2an = (float*)((char*)d_ws + 65536);          // 512 B
  float*  wax  = (float*)((char*)d_ws + 66048);          // 512 B

  pack_weights_kernel<<<64, 256, 0, stream>>>(W, W2, a, Wp, W2p, w2an, wax);
  node_kernel<<<N / NB, 256, 0, stream>>>(input, neigh, edge, a, w2an, wax,
                                          Wp, W2p, out);
}